// Round 12
// baseline (213.863 us; speedup 1.0000x reference)
//
#include <hip/hip_runtime.h>
#include <cmath>

#define K_SEG 50
#define ITERS 10
#define NPASS (ITERS + 1)       // 10 updates + final labeling pass
#define H_IMG 512
#define W_IMG 512
#define NPIX (H_IMG * W_IMG)
#define BATCH 16
#define SLOTS (K_SEG * 6)       // 300 doubles per image
#define TOTAL_SLOTS (NPASS * BATCH * SLOTS)

// ws: gsums[NPASS][BATCH][SLOTS]  = 422400 B
// slot layout: [0]=r [1]=g [2]=b [3]=SUM(row) [4]=SUM(col) [5]=count
// (rows/cols are exact small ints in fp32 sums; scaled by ratiof at block flush)

__global__ void zero_all(double* __restrict__ g) {
    int i = blockIdx.x * 256 + threadIdx.x;
    if (i < TOTAL_SLOTS) g[i] = 0.0;
}

// One pass: centers from gsums[it-1] (or grid-init), label a 64x64 tile,
// wave-segmented-reduce runs, accumulate per-segment sums into gsums[it].
// This is the R9 kernel verbatim (proven 213-214us, absmax 8.9e-16 twice).
__global__ void __launch_bounds__(256) assign_fused(
        const float* __restrict__ x, double* __restrict__ gsums,
        int it, float ratiof) {
    __shared__ float cen[K_SEG][6];     // r,g,b,cy,cx,h2(=0.5*c.c)
    __shared__ float cmax[K_SEG];       // exact per-center max color-dist^2
    __shared__ double part[K_SEG][6];
    __shared__ int klist4[4][52];
    __shared__ int ncand4[4];

    int t = threadIdx.x;
    int tx = blockIdx.x, ty = blockIdx.y, b = blockIdx.z;
    const float* xb = x + (size_t)b * 3 * NPIX;

    // ---- centers for this pass (identical fp32 math in every block) ----
    if (it == 0) {
        if (t < K_SEG) {
            int i = t >> 3, j = t & 7;
            int y = 32 + 64 * i, xc = 32 + 64 * j;   // grid init
            int p = y * W_IMG + xc;
            float r = xb[p], g = xb[NPIX + p], bl = xb[2 * NPIX + p];
            float cfy = (float)y * ratiof, cfx = (float)xc * ratiof;
            cen[t][0]=r; cen[t][1]=g; cen[t][2]=bl; cen[t][3]=cfy; cen[t][4]=cfx;
            cen[t][5] = 0.5f * ((((r*r + g*g) + bl*bl) + cfy*cfy) + cfx*cfx);
            float m0 = fmaxf(r, 1.0f - r), m1 = fmaxf(g, 1.0f - g), m2 = fmaxf(bl, 1.0f - bl);
            cmax[t] = (m0*m0 + m1*m1) + m2*m2;
        }
    } else {
        const double* gp = gsums + ((size_t)(it - 1) * BATCH + b) * SLOTS;
        for (int i = t; i < SLOTS; i += 256) ((double*)part)[i] = gp[i];
        __syncthreads();
        if (t < K_SEG) {
            double cv = part[t][5];
            double denom = cv > 1.0 ? cv : 1.0;
            double rcp = 1.0 / denom;        // one fp64 divide, then 5 muls
            float c0 = (float)(part[t][0] * rcp);
            float c1 = (float)(part[t][1] * rcp);
            float c2v = (float)(part[t][2] * rcp);
            float c3 = (float)(part[t][3] * rcp);
            float c4 = (float)(part[t][4] * rcp);
            cen[t][0]=c0; cen[t][1]=c1; cen[t][2]=c2v; cen[t][3]=c3; cen[t][4]=c4;
            cen[t][5] = 0.5f * ((((c0*c0 + c1*c1) + c2v*c2v) + c3*c3) + c4*c4);
            float m0 = fmaxf(c0, 1.0f - c0), m1 = fmaxf(c1, 1.0f - c1), m2 = fmaxf(c2v, 1.0f - c2v);
            cmax[t] = (m0*m0 + m1*m1) + m2*m2;
        }
    }
    __syncthreads();

    // ---- exact per-WAVE spatial pruning (16-row x 64-col rect) ----
    int wid = t >> 6;
    int lane = t & 63;
    {
        float Rmin = INFINITY, val = INFINITY;
        if (lane < K_SEG) {
            float cy = cen[lane][3], cxx = cen[lane][4];
            float y0 = (float)(ty * 64 + wid * 16) * ratiof;
            float y1 = (float)(ty * 64 + wid * 16 + 15) * ratiof;
            float x0 = (float)(tx * 64) * ratiof;
            float x1 = (float)(tx * 64 + 63) * ratiof;
            float dyn = fmaxf(fmaxf(y0 - cy, cy - y1), 0.0f);
            float dxn = fmaxf(fmaxf(x0 - cxx, cxx - x1), 0.0f);
            float dyf = fmaxf(cy - y0, y1 - cy);
            float dxf = fmaxf(cxx - x0, x1 - cxx);
            Rmin = dyn * dyn + dxn * dxn;
            val = (dyf * dyf + dxf * dxf) + cmax[lane];
        }
        float u = val;
        for (int off = 32; off; off >>= 1) u = fminf(u, __shfl_xor(u, off));
        bool cand = (lane < K_SEG) && (Rmin <= u + 0.25f);  // eps >> fp32 rounding
        unsigned long long m = __ballot(cand);
        if (cand) {
            int pos = __popcll(m & ((1ull << lane) - 1ull));
            klist4[wid][pos] = lane;   // ascending k -> argmin first-min tie rule kept
        }
        if (lane == 0) ncand4[wid] = __popcll(m);
    }
    for (int i = t; i < SLOTS; i += 256) ((double*)part)[i] = 0.0;
    __syncthreads();
    int nc = ncand4[wid];

    // ---- labels (16 px/thread in 2 halves) + run accumulation ----
    int row = t >> 2;                 // 0..63 within tile; wave = rows 16w..16w+15
    int colq = (t & 3) << 4;
    int gy = ty * 64 + row;
    int gx0 = tx * 64 + colq;
    float fy = (float)gy * ratiof;

    int runlab = -1;
    float sr = 0.0f, sg = 0.0f, sb = 0.0f, scol = 0.0f;
    int rn = 0;
    for (int h = 0; h < 2; ++h) {
        int gx = gx0 + h * 8;
        size_t p = (size_t)gy * W_IMG + gx;
        float4 ra = *(const float4*)(xb + p);
        float4 rb4 = *(const float4*)(xb + p + 4);
        float4 ga = *(const float4*)(xb + NPIX + p);
        float4 gb4 = *(const float4*)(xb + NPIX + p + 4);
        float4 ba = *(const float4*)(xb + 2 * NPIX + p);
        float4 bb4 = *(const float4*)(xb + 2 * NPIX + p + 4);
        float rr[8] = {ra.x, ra.y, ra.z, ra.w, rb4.x, rb4.y, rb4.z, rb4.w};
        float gg[8] = {ga.x, ga.y, ga.z, ga.w, gb4.x, gb4.y, gb4.z, gb4.w};
        float bv[8] = {ba.x, ba.y, ba.z, ba.w, bb4.x, bb4.y, bb4.z, bb4.w};
        float fx8[8], best8[8];
        int lab8[8];
#pragma unroll
        for (int u2 = 0; u2 < 8; ++u2) {
            fx8[u2] = (float)(gx + u2) * ratiof;   // same expr: labels identical
            best8[u2] = INFINITY;
            lab8[u2] = 0;
        }
        for (int c = 0; c < nc; ++c) {
            int k = klist4[wid][c];
            float c0 = cen[k][0], c1 = cen[k][1], c2v = cen[k][2];
            float c3 = cen[k][3], c4 = cen[k][4], h2 = cen[k][5];
            float base = fmaf(fy, -c3, h2);
#pragma unroll
            for (int u2 = 0; u2 < 8; ++u2) {
                float s = fmaf(rr[u2], -c0, base);
                s = fmaf(gg[u2], -c1, s);
                s = fmaf(bv[u2], -c2v, s);
                s = fmaf(fx8[u2], -c4, s);
                if (s < best8[u2]) { best8[u2] = s; lab8[u2] = k; }
            }
        }
#pragma unroll
        for (int u2 = 0; u2 < 8; ++u2) {
            if (lab8[u2] != runlab) {
                if (rn > 0) {   // mid-thread run boundary: rare inline flush
                    double* pp = part[runlab];
                    unsafeAtomicAdd(&pp[0], (double)sr);
                    unsafeAtomicAdd(&pp[1], (double)sg);
                    unsafeAtomicAdd(&pp[2], (double)sb);
                    unsafeAtomicAdd(&pp[3], (double)((float)(gy * rn)));  // exact int
                    unsafeAtomicAdd(&pp[4], (double)scol);                 // exact int
                    unsafeAtomicAdd(&pp[5], (double)rn);
                }
                runlab = lab8[u2];
                sr = rr[u2]; sg = gg[u2]; sb = bv[u2]; scol = (float)(gx + u2); rn = 1;
            } else {
                sr += rr[u2]; sg += gg[u2]; sb += bv[u2]; scol += (float)(gx + u2); rn += 1;
            }
        }
    }

    // ---- wave-segmented reduction of final runs (2-4 distinct labels/wave) ----
    {
        float fsr = sr, fsg = sg, fsb = sb, fscol = scol;
        float fsrow = (float)(gy * rn);     // <= 511*16, exact
        float frn = (float)rn;
        unsigned long long remaining = __ballot(true);
        while (remaining) {
            int leader = __ffsll((unsigned long long)remaining) - 1;
            int labL = __shfl(runlab, leader);
            bool in = (runlab == labL);
            unsigned long long grp = __ballot(in);
            float a0 = in ? fsr : 0.0f, a1 = in ? fsg : 0.0f, a2 = in ? fsb : 0.0f;
            float a3 = in ? fsrow : 0.0f, a4 = in ? fscol : 0.0f, a5 = in ? frn : 0.0f;
#pragma unroll
            for (int off = 1; off < 64; off <<= 1) {
                a0 += __shfl_xor(a0, off);
                a1 += __shfl_xor(a1, off);
                a2 += __shfl_xor(a2, off);
                a3 += __shfl_xor(a3, off);
                a4 += __shfl_xor(a4, off);
                a5 += __shfl_xor(a5, off);
            }
            if (lane == leader) {
                double* pp = part[labL];
                unsafeAtomicAdd(&pp[0], (double)a0);
                unsafeAtomicAdd(&pp[1], (double)a1);
                unsafeAtomicAdd(&pp[2], (double)a2);
                unsafeAtomicAdd(&pp[3], (double)a3);
                unsafeAtomicAdd(&pp[4], (double)a4);
                unsafeAtomicAdd(&pp[5], (double)a5);
            }
            remaining &= ~grp;
        }
    }
    __syncthreads();

    // ---- flush block partials to this pass's global sums (scale row/col) ----
    double* gp = gsums + ((size_t)it * BATCH + b) * SLOTS;
    for (int i = t; i < SLOTS; i += 256) {
        double v = ((double*)part)[i];
        int slot = i % 6;
        if (slot == 3 || slot == 4) v *= (double)ratiof;
        if (v != 0.0) unsafeAtomicAdd(&gp[i], v);
    }
}

__global__ void finalize_kernel(const double* __restrict__ gsums, float* __restrict__ out) {
    int t = threadIdx.x;
    if (t < BATCH) {
        const double* gp = gsums + ((size_t)ITERS * BATCH + t) * SLOTS;
        double sr = 0.0, sg = 0.0, sb = 0.0;
        for (int k = 0; k < K_SEG; ++k) {
            const double* s = gp + k * 6;
            double cv = s[5];
            float cntf = (float)(cv > 1.0 ? cv : 1.0);
            float wf = 1.0f / cntf;  // fp32 rounding like reference w
            sr += s[0] * (double)wf;
            sg += s[1] * (double)wf;
            sb += s[2] * (double)wf;
        }
        double mr = sr / (double)NPIX, mg = sg / (double)NPIX, mb = sb / (double)NPIX;
        double Drg = (mr - mg) * (mr - mg);
        double Drb = (mr - mb) * (mr - mb);
        double Dgb = (mb - mg) * (mb - mg);
        out[t] = (float)sqrt(Drg * Drg + Drb * Drb + Dgb * Dgb);
    }
}

extern "C" void kernel_launch(void* const* d_in, const int* in_sizes, int n_in,
                              void* d_out, int out_size, void* d_ws, size_t ws_size,
                              hipStream_t stream) {
    const float* x = (const float*)d_in[0];
    float* out = (float*)d_out;
    double* gsums = (double*)d_ws;

    double S = sqrt((double)NPIX / (double)K_SEG);
    float ratiof = (float)(10.0 / S);

    zero_all<<<(TOTAL_SLOTS + 255) / 256, 256, 0, stream>>>(gsums);
    dim3 agrid(W_IMG / 64, H_IMG / 64, BATCH);   // 1024 blocks, proven R9 geometry
    for (int it = 0; it < NPASS; ++it)
        assign_fused<<<agrid, 256, 0, stream>>>(x, gsums, it, ratiof);
    finalize_kernel<<<1, 64, 0, stream>>>(gsums, out);
}

// Round 13
// 203.714 us; speedup vs baseline: 1.0498x; 1.0498x over previous
//
#include <hip/hip_runtime.h>
#include <cmath>

#define K_SEG 50
#define ITERS 10
#define NPASS (ITERS + 1)       // 10 updates + final labeling pass
#define H_IMG 512
#define W_IMG 512
#define NPIX (H_IMG * W_IMG)
#define BATCH 16
#define SLOTS (K_SEG * 6)       // 300 doubles per image
#define TOTAL_SLOTS (NPASS * BATCH * SLOTS)
#define TPB 512                 // 8 waves/block; 4 blocks/CU = 2048 thr = CU max

// ws: gsums[NPASS][BATCH][SLOTS]  = 422400 B
// slot layout: [0]=r [1]=g [2]=b [3]=SUM(row) [4]=SUM(col) [5]=count
// (rows/cols are exact small ints in fp32 sums; scaled by ratiof at block flush)

__global__ void zero_all(double* __restrict__ g) {
    int i = blockIdx.x * 256 + threadIdx.x;
    if (i < TOTAL_SLOTS) g[i] = 0.0;
}

// One pass: centers from gsums[it-1] (or grid-init), label a 64x64 tile,
// wave-segmented-reduce runs, accumulate per-segment sums into gsums[it].
// Same label-determining fp32 expressions as R9/R12 (proven absmax 8.9e-16 x3).
// Change vs R12: 512 thr/block, 8 px/thread -> 32 waves/CU (was 16).
__global__ void __launch_bounds__(TPB) assign_fused(
        const float* __restrict__ x, double* __restrict__ gsums,
        int it, float ratiof) {
    __shared__ float cen[K_SEG][6];     // r,g,b,cy,cx,h2(=0.5*c.c)
    __shared__ float cmax[K_SEG];       // exact per-center max color-dist^2
    __shared__ double part[K_SEG][6];
    __shared__ int klist8[8][52];
    __shared__ int ncand8[8];

    int t = threadIdx.x;
    int tx = blockIdx.x, ty = blockIdx.y, b = blockIdx.z;
    const float* xb = x + (size_t)b * 3 * NPIX;

    // ---- centers for this pass (identical fp32 math in every block) ----
    if (it == 0) {
        if (t < K_SEG) {
            int i = t >> 3, j = t & 7;
            int y = 32 + 64 * i, xc = 32 + 64 * j;   // grid init
            int p = y * W_IMG + xc;
            float r = xb[p], g = xb[NPIX + p], bl = xb[2 * NPIX + p];
            float cfy = (float)y * ratiof, cfx = (float)xc * ratiof;
            cen[t][0]=r; cen[t][1]=g; cen[t][2]=bl; cen[t][3]=cfy; cen[t][4]=cfx;
            cen[t][5] = 0.5f * ((((r*r + g*g) + bl*bl) + cfy*cfy) + cfx*cfx);
            float m0 = fmaxf(r, 1.0f - r), m1 = fmaxf(g, 1.0f - g), m2 = fmaxf(bl, 1.0f - bl);
            cmax[t] = (m0*m0 + m1*m1) + m2*m2;
        }
    } else {
        const double* gp = gsums + ((size_t)(it - 1) * BATCH + b) * SLOTS;
        for (int i = t; i < SLOTS; i += TPB) ((double*)part)[i] = gp[i];
        __syncthreads();
        if (t < K_SEG) {
            double cv = part[t][5];
            double denom = cv > 1.0 ? cv : 1.0;
            double rcp = 1.0 / denom;        // one fp64 divide, then 5 muls
            float c0 = (float)(part[t][0] * rcp);
            float c1 = (float)(part[t][1] * rcp);
            float c2v = (float)(part[t][2] * rcp);
            float c3 = (float)(part[t][3] * rcp);
            float c4 = (float)(part[t][4] * rcp);
            cen[t][0]=c0; cen[t][1]=c1; cen[t][2]=c2v; cen[t][3]=c3; cen[t][4]=c4;
            cen[t][5] = 0.5f * ((((c0*c0 + c1*c1) + c2v*c2v) + c3*c3) + c4*c4);
            float m0 = fmaxf(c0, 1.0f - c0), m1 = fmaxf(c1, 1.0f - c1), m2 = fmaxf(c2v, 1.0f - c2v);
            cmax[t] = (m0*m0 + m1*m1) + m2*m2;
        }
    }
    __syncthreads();

    // ---- exact per-WAVE spatial pruning (8-row x 64-col rect) ----
    int wid = t >> 6;        // 0..7
    int lane = t & 63;
    {
        float Rmin = INFINITY, val = INFINITY;
        if (lane < K_SEG) {
            float cy = cen[lane][3], cxx = cen[lane][4];
            float y0 = (float)(ty * 64 + wid * 8) * ratiof;
            float y1 = (float)(ty * 64 + wid * 8 + 7) * ratiof;
            float x0 = (float)(tx * 64) * ratiof;
            float x1 = (float)(tx * 64 + 63) * ratiof;
            float dyn = fmaxf(fmaxf(y0 - cy, cy - y1), 0.0f);
            float dxn = fmaxf(fmaxf(x0 - cxx, cxx - x1), 0.0f);
            float dyf = fmaxf(cy - y0, y1 - cy);
            float dxf = fmaxf(cxx - x0, x1 - cxx);
            Rmin = dyn * dyn + dxn * dxn;
            val = (dyf * dyf + dxf * dxf) + cmax[lane];
        }
        float u = val;
        for (int off = 32; off; off >>= 1) u = fminf(u, __shfl_xor(u, off));
        bool cand = (lane < K_SEG) && (Rmin <= u + 0.25f);  // eps >> fp32 rounding
        unsigned long long m = __ballot(cand);
        if (cand) {
            int pos = __popcll(m & ((1ull << lane) - 1ull));
            klist8[wid][pos] = lane;   // ascending k -> argmin first-min tie rule kept
        }
        if (lane == 0) ncand8[wid] = __popcll(m);
    }
    for (int i = t; i < SLOTS; i += TPB) ((double*)part)[i] = 0.0;
    __syncthreads();
    int nc = ncand8[wid];

    // ---- labels (8 px/thread) + run accumulation ----
    int row = t >> 3;                 // 0..63; wave covers rows 8*wid..8*wid+7
    int col8 = (t & 7) << 3;          // 0,8,...,56
    int gy = ty * 64 + row;
    int gx = tx * 64 + col8;
    float fy = (float)gy * ratiof;

    size_t p = (size_t)gy * W_IMG + gx;
    float4 ra = *(const float4*)(xb + p);
    float4 rb4 = *(const float4*)(xb + p + 4);
    float4 ga = *(const float4*)(xb + NPIX + p);
    float4 gb4 = *(const float4*)(xb + NPIX + p + 4);
    float4 ba = *(const float4*)(xb + 2 * NPIX + p);
    float4 bb4 = *(const float4*)(xb + 2 * NPIX + p + 4);
    float rr[8] = {ra.x, ra.y, ra.z, ra.w, rb4.x, rb4.y, rb4.z, rb4.w};
    float gg[8] = {ga.x, ga.y, ga.z, ga.w, gb4.x, gb4.y, gb4.z, gb4.w};
    float bv[8] = {ba.x, ba.y, ba.z, ba.w, bb4.x, bb4.y, bb4.z, bb4.w};
    float fx8[8], best8[8];
    int lab8[8];
#pragma unroll
    for (int u2 = 0; u2 < 8; ++u2) {
        fx8[u2] = (float)(gx + u2) * ratiof;   // same expr: labels identical
        best8[u2] = INFINITY;
        lab8[u2] = 0;
    }
    for (int c = 0; c < nc; ++c) {
        int k = klist8[wid][c];
        float c0 = cen[k][0], c1 = cen[k][1], c2v = cen[k][2];
        float c3 = cen[k][3], c4 = cen[k][4], h2 = cen[k][5];
        float base = fmaf(fy, -c3, h2);
#pragma unroll
        for (int u2 = 0; u2 < 8; ++u2) {
            float s = fmaf(rr[u2], -c0, base);
            s = fmaf(gg[u2], -c1, s);
            s = fmaf(bv[u2], -c2v, s);
            s = fmaf(fx8[u2], -c4, s);
            if (s < best8[u2]) { best8[u2] = s; lab8[u2] = k; }
        }
    }
    int runlab = -1;
    float sr = 0.0f, sg = 0.0f, sb = 0.0f, scol = 0.0f;
    int rn = 0;
#pragma unroll
    for (int u2 = 0; u2 < 8; ++u2) {
        if (lab8[u2] != runlab) {
            if (rn > 0) {   // mid-thread run boundary: rare inline flush
                double* pp = part[runlab];
                unsafeAtomicAdd(&pp[0], (double)sr);
                unsafeAtomicAdd(&pp[1], (double)sg);
                unsafeAtomicAdd(&pp[2], (double)sb);
                unsafeAtomicAdd(&pp[3], (double)((float)(gy * rn)));  // exact int
                unsafeAtomicAdd(&pp[4], (double)scol);                 // exact int
                unsafeAtomicAdd(&pp[5], (double)rn);
            }
            runlab = lab8[u2];
            sr = rr[u2]; sg = gg[u2]; sb = bv[u2]; scol = (float)(gx + u2); rn = 1;
        } else {
            sr += rr[u2]; sg += gg[u2]; sb += bv[u2]; scol += (float)(gx + u2); rn += 1;
        }
    }

    // ---- wave-segmented reduction of final runs (2-4 distinct labels/wave) ----
    {
        float fsr = sr, fsg = sg, fsb = sb, fscol = scol;
        float fsrow = (float)(gy * rn);     // <= 511*8, exact
        float frn = (float)rn;
        unsigned long long remaining = __ballot(true);
        while (remaining) {
            int leader = __ffsll((unsigned long long)remaining) - 1;
            int labL = __shfl(runlab, leader);
            bool in = (runlab == labL);
            unsigned long long grp = __ballot(in);
            float a0 = in ? fsr : 0.0f, a1 = in ? fsg : 0.0f, a2 = in ? fsb : 0.0f;
            float a3 = in ? fsrow : 0.0f, a4 = in ? fscol : 0.0f, a5 = in ? frn : 0.0f;
#pragma unroll
            for (int off = 1; off < 64; off <<= 1) {
                a0 += __shfl_xor(a0, off);
                a1 += __shfl_xor(a1, off);
                a2 += __shfl_xor(a2, off);
                a3 += __shfl_xor(a3, off);
                a4 += __shfl_xor(a4, off);
                a5 += __shfl_xor(a5, off);
            }
            if (lane == leader) {
                double* pp = part[labL];
                unsafeAtomicAdd(&pp[0], (double)a0);
                unsafeAtomicAdd(&pp[1], (double)a1);
                unsafeAtomicAdd(&pp[2], (double)a2);
                unsafeAtomicAdd(&pp[3], (double)a3);
                unsafeAtomicAdd(&pp[4], (double)a4);
                unsafeAtomicAdd(&pp[5], (double)a5);
            }
            remaining &= ~grp;
        }
    }
    __syncthreads();

    // ---- flush block partials to this pass's global sums (scale row/col) ----
    double* gp = gsums + ((size_t)it * BATCH + b) * SLOTS;
    for (int i = t; i < SLOTS; i += TPB) {
        double v = ((double*)part)[i];
        int slot = i % 6;
        if (slot == 3 || slot == 4) v *= (double)ratiof;
        if (v != 0.0) unsafeAtomicAdd(&gp[i], v);
    }
}

__global__ void finalize_kernel(const double* __restrict__ gsums, float* __restrict__ out) {
    int t = threadIdx.x;
    if (t < BATCH) {
        const double* gp = gsums + ((size_t)ITERS * BATCH + t) * SLOTS;
        double sr = 0.0, sg = 0.0, sb = 0.0;
        for (int k = 0; k < K_SEG; ++k) {
            const double* s = gp + k * 6;
            double cv = s[5];
            float cntf = (float)(cv > 1.0 ? cv : 1.0);
            float wf = 1.0f / cntf;  // fp32 rounding like reference w
            sr += s[0] * (double)wf;
            sg += s[1] * (double)wf;
            sb += s[2] * (double)wf;
        }
        double mr = sr / (double)NPIX, mg = sg / (double)NPIX, mb = sb / (double)NPIX;
        double Drg = (mr - mg) * (mr - mg);
        double Drb = (mr - mb) * (mr - mb);
        double Dgb = (mb - mg) * (mb - mg);
        out[t] = (float)sqrt(Drg * Drg + Drb * Drb + Dgb * Dgb);
    }
}

extern "C" void kernel_launch(void* const* d_in, const int* in_sizes, int n_in,
                              void* d_out, int out_size, void* d_ws, size_t ws_size,
                              hipStream_t stream) {
    const float* x = (const float*)d_in[0];
    float* out = (float*)d_out;
    double* gsums = (double*)d_ws;

    double S = sqrt((double)NPIX / (double)K_SEG);
    float ratiof = (float)(10.0 / S);

    zero_all<<<(TOTAL_SLOTS + 255) / 256, 256, 0, stream>>>(gsums);
    dim3 agrid(W_IMG / 64, H_IMG / 64, BATCH);   // 1024 blocks, 64x64 tiles
    for (int it = 0; it < NPASS; ++it)
        assign_fused<<<agrid, TPB, 0, stream>>>(x, gsums, it, ratiof);
    finalize_kernel<<<1, 64, 0, stream>>>(gsums, out);
}